// Round 1
// baseline (334.580 us; speedup 1.0000x reference)
//
#include <hip/hip_runtime.h>
#include <stdint.h>

#define N_ROWS 8192
#define D_DIM  1024
#define BK     32
#define NT     (D_DIM / BK)   // 32 K-tiles

typedef __attribute__((ext_vector_type(8))) __bf16 bf16x8;
typedef __attribute__((ext_vector_type(4))) float  f32x4;

#define GLD16(gptr, lptr) __builtin_amdgcn_global_load_lds( \
    (const __attribute__((address_space(1))) void*)(gptr),  \
    (__attribute__((address_space(3))) void*)(lptr), 16, 0, 0)

__device__ __forceinline__ unsigned short f2bf(float v) {
    unsigned int u = __float_as_uint(v);
    u += 0x7fffu + ((u >> 16) & 1u);   // RNE
    return (unsigned short)(u >> 16);
}

// Fused: img -> bf16 (pre-scaled by logit_scale*log2e), txt -> bf16,
// and exact fp32 diag[i] = scale * dot(img[i], txt[i]).
// One block per row; 256 threads, one float4 of each input per thread.
__global__ void preprocess_kernel(const float* __restrict__ img,
                                  const float* __restrict__ txt,
                                  const float* __restrict__ scale_p,
                                  short* __restrict__ imgbf,
                                  short* __restrict__ txtbf,
                                  float* __restrict__ diag) {
    const int row = blockIdx.x;
    const int tid = threadIdx.x;
    const float sc = *scale_p;
    const float f  = sc * 1.44269504088896340736f;   // fold log2(e) for exp2 epilogue

    const float4 x = ((const float4*)(img + (size_t)row * D_DIM))[tid];
    const float4 y = ((const float4*)(txt + (size_t)row * D_DIM))[tid];

    short4 oi, ot;
    oi.x = (short)f2bf(x.x * f); oi.y = (short)f2bf(x.y * f);
    oi.z = (short)f2bf(x.z * f); oi.w = (short)f2bf(x.w * f);
    ot.x = (short)f2bf(y.x);     ot.y = (short)f2bf(y.y);
    ot.z = (short)f2bf(y.z);     ot.w = (short)f2bf(y.w);
    ((short4*)(imgbf + (size_t)row * D_DIM))[tid] = oi;
    ((short4*)(txtbf + (size_t)row * D_DIM))[tid] = ot;

    float s = x.x * y.x + x.y * y.y + x.z * y.z + x.w * y.w;
#pragma unroll
    for (int m = 1; m < 64; m <<= 1) s += __shfl_xor(s, m);
    __shared__ float ws[4];
    if ((tid & 63) == 0) ws[tid >> 6] = s;
    __syncthreads();
    if (tid == 0) diag[row] = (ws[0] + ws[1] + ws[2] + ws[3]) * sc;
}

// 256x256 tile, 8 waves (2Mx4N), BK=32, ring-of-4 LDS (128 KiB),
// counted vmcnt(8) once per K-tile (prefetch distance 3 K-tiles).
// Epilogue: e = exp2(acc), row/col sums via shuffle + atomics.
__global__ __launch_bounds__(512, 2)
void gemm_exp_kernel(const short* __restrict__ A,   // img bf16, scaled by scale*log2e
                     const short* __restrict__ B,   // txt bf16
                     float* __restrict__ row_sum,
                     float* __restrict__ col_sum) {
    __shared__ __align__(16) short As[4][256 * BK];
    __shared__ __align__(16) short Bs[4][256 * BK];

    const int tid  = threadIdx.x;
    const int lane = tid & 63;
    const int w    = tid >> 6;      // wave 0..7
    const int wm   = w >> 2;        // 0..1  (M half)
    const int wn   = w & 3;         // 0..3  (N quarter)
    const int ti   = blockIdx.y * 256;
    const int tj   = blockIdx.x * 256;
    const int quad = lane >> 4;
    const int l15  = lane & 15;

    // ---- staging addresses (pre-swizzled global source, linear LDS dest) ----
    // chunk g = issue*512 + tid ; row r = g>>2, pos p = g&3, src chunk = p ^ (r&3)
    const int sr = tid >> 2;                   // 0..127 (issue 0 row)
    const int sp = (tid & 3) ^ (sr & 3);       // pre-swizzled 16B chunk
    const size_t aoff0 = (size_t)(ti + sr) * D_DIM + sp * 8;
    const size_t aoff1 = aoff0 + (size_t)128 * D_DIM;   // issue 1: rows +128 (r&3 unchanged)
    const size_t boff0 = (size_t)(tj + sr) * D_DIM + sp * 8;
    const size_t boff1 = boff0 + (size_t)128 * D_DIM;
    const int sdst0 = w * 512;                 // wave-uniform LDS base (shorts), issue 0
    const int sdst1 = 4096 + w * 512;          // issue 1

    // ---- fragment read addresses (swizzled) ----
    // row = (half)*X + fr*16 + l15 ; chunk = quad ^ (row&3) = quad ^ (lane&3)
    const int fchunk = quad ^ (lane & 3);
    const int abase  = (wm * 128 + l15) * BK + fchunk * 8;
    const int bbase  = (wn * 64  + l15) * BK + fchunk * 8;

    f32x4 acc[8][4];
#pragma unroll
    for (int i = 0; i < 8; i++)
#pragma unroll
        for (int j = 0; j < 4; j++) acc[i][j] = (f32x4){0.f, 0.f, 0.f, 0.f};

    // ---- prologue: stage K-tiles 0,1,2 (12 loads/thread) ----
#pragma unroll
    for (int t = 0; t < 3; ++t) {
        const int kp = t * BK;
        GLD16(A + aoff0 + kp, &As[t][sdst0]);
        GLD16(A + aoff1 + kp, &As[t][sdst1]);
        GLD16(B + boff0 + kp, &Bs[t][sdst0]);
        GLD16(B + boff1 + kp, &Bs[t][sdst1]);
    }
    asm volatile("s_waitcnt vmcnt(8)" ::: "memory");   // tile 0 landed; 1,2 in flight
    __builtin_amdgcn_s_barrier();

    // ---- main loop: 2 phases per K-tile, one counted vmcnt per K-tile ----
    for (int t = 0; t < NT; ++t) {
        const int buf  = t & 3;
        const int pbuf = (t + 3) & 3;
        const int kp   = ((t + 3 < NT) ? (t + 3) : (NT - 1)) * BK;  // clamp: dead-slot reload
        const short* as = As[buf];
        const short* bs = Bs[buf];

        bf16x8 af[4], bfr[4];

        // ---- phase 0: frags (fr 0-3 x fc 0-3), prefetch A(t+3) ----
#pragma unroll
        for (int fr = 0; fr < 4; ++fr) af[fr]  = *(const bf16x8*)(as + abase + fr * 512);
#pragma unroll
        for (int fc = 0; fc < 4; ++fc) bfr[fc] = *(const bf16x8*)(bs + bbase + fc * 512);
        GLD16(A + aoff0 + kp, &As[pbuf][sdst0]);
        GLD16(A + aoff1 + kp, &As[pbuf][sdst1]);
        __builtin_amdgcn_s_barrier();
        __builtin_amdgcn_s_setprio(1);
#pragma unroll
        for (int fr = 0; fr < 4; ++fr)
#pragma unroll
            for (int fc = 0; fc < 4; ++fc)
                acc[fr][fc] = __builtin_amdgcn_mfma_f32_16x16x32_bf16(
                    af[fr], bfr[fc], acc[fr][fc], 0, 0, 0);
        __builtin_amdgcn_s_setprio(0);
        __builtin_amdgcn_s_barrier();

        // ---- phase 1: frags (fr 4-7 x fc 0-3, B reused), prefetch B(t+3) ----
#pragma unroll
        for (int fr = 0; fr < 4; ++fr) af[fr] = *(const bf16x8*)(as + abase + (4 + fr) * 512);
        GLD16(B + boff0 + kp, &Bs[pbuf][sdst0]);
        GLD16(B + boff1 + kp, &Bs[pbuf][sdst1]);
        __builtin_amdgcn_s_barrier();
        __builtin_amdgcn_s_setprio(1);
#pragma unroll
        for (int fr = 0; fr < 4; ++fr)
#pragma unroll
            for (int fc = 0; fc < 4; ++fc)
                acc[4 + fr][fc] = __builtin_amdgcn_mfma_f32_16x16x32_bf16(
                    af[fr], bfr[fc], acc[4 + fr][fc], 0, 0, 0);
        __builtin_amdgcn_s_setprio(0);
        // counted wait: allow tiles t+2, t+3 (8 loads) in flight; t+1 guaranteed landed
        asm volatile("s_waitcnt vmcnt(8)" ::: "memory");
        __builtin_amdgcn_s_barrier();
    }

    // ---- epilogue: e = 2^acc, row/col reductions ----
#pragma unroll
    for (int fr = 0; fr < 8; ++fr)
#pragma unroll
        for (int fc = 0; fc < 4; ++fc)
#pragma unroll
            for (int r = 0; r < 4; ++r)
                acc[fr][fc][r] = __builtin_amdgcn_exp2f(acc[fr][fc][r]);

    // element (fr,fc,r) = logits[ti + wm*128 + fr*16 + quad*4 + r][tj + wn*64 + fc*16 + l15]
    const int rowbase = ti + wm * 128;
#pragma unroll
    for (int fr = 0; fr < 8; ++fr) {
#pragma unroll
        for (int r = 0; r < 4; ++r) {
            float s = acc[fr][0][r] + acc[fr][1][r] + acc[fr][2][r] + acc[fr][3][r];
            s += __shfl_xor(s, 1);
            s += __shfl_xor(s, 2);
            s += __shfl_xor(s, 4);
            s += __shfl_xor(s, 8);
            if (l15 == 0)
                atomicAdd(&row_sum[rowbase + fr * 16 + quad * 4 + r], s);
        }
    }

    const int colbase = tj + wn * 64;
#pragma unroll
    for (int fc = 0; fc < 4; ++fc) {
        float s = 0.f;
#pragma unroll
        for (int fr = 0; fr < 8; ++fr)
#pragma unroll
            for (int r = 0; r < 4; ++r) s += acc[fr][fc][r];
        s += __shfl_xor(s, 16);
        s += __shfl_xor(s, 32);
        if (quad == 0)
            atomicAdd(&col_sum[colbase + fc * 16 + l15], s);
    }
}

__global__ void finish_kernel(const float* __restrict__ rs, const float* __restrict__ cs,
                              const float* __restrict__ diag, float* __restrict__ out) {
    const int tid  = threadIdx.x;
    const int lane = tid & 63;
    const int w    = tid >> 6;
    float s = 0.f;
    for (int i = tid; i < N_ROWS; i += 256)
        s += logf(rs[i]) + logf(cs[i]) - 2.0f * diag[i];
#pragma unroll
    for (int m = 1; m < 64; m <<= 1) s += __shfl_xor(s, m);
    __shared__ float wsum[4];
    if (lane == 0) wsum[w] = s;
    __syncthreads();
    if (tid == 0)
        out[0] = (wsum[0] + wsum[1] + wsum[2] + wsum[3]) * (0.5f / (float)N_ROWS);
}

extern "C" void kernel_launch(void* const* d_in, const int* in_sizes, int n_in,
                              void* d_out, int out_size, void* d_ws, size_t ws_size,
                              hipStream_t stream) {
    const float* img     = (const float*)d_in[0];
    const float* txt     = (const float*)d_in[1];
    const float* scale_p = (const float*)d_in[2];
    float* out = (float*)d_out;

    char* ws = (char*)d_ws;
    short* imgbf   = (short*)ws;                                  // 16 MB
    short* txtbf   = (short*)(ws + (size_t)16 * 1024 * 1024);     // 16 MB
    float* row_sum = (float*)(ws + (size_t)32 * 1024 * 1024);     // 32 KB
    float* col_sum = row_sum + N_ROWS;                            // 32 KB
    float* diag    = col_sum + N_ROWS;                            // 32 KB

    hipMemsetAsync(row_sum, 0, 2 * N_ROWS * sizeof(float), stream);

    preprocess_kernel<<<N_ROWS, 256, 0, stream>>>(img, txt, scale_p, imgbf, txtbf, diag);

    dim3 grid(N_ROWS / 256, N_ROWS / 256);
    gemm_exp_kernel<<<grid, 512, 0, stream>>>(imgbf, txtbf, row_sum, col_sum);

    finish_kernel<<<1, 256, 0, stream>>>(row_sum, col_sum, diag, out);
}

// Round 2
// 326.595 us; speedup vs baseline: 1.0245x; 1.0245x over previous
//
#include <hip/hip_runtime.h>
#include <stdint.h>

#define N_ROWS 8192
#define D_DIM  1024
#define KH     32                 // K-half (pipeline unit) width
#define NU     (D_DIM / KH)       // 32 units
#define SLOT   (256 * KH)         // 8192 shorts = 16 KiB per slot

typedef __attribute__((ext_vector_type(8))) __bf16 bf16x8;
typedef __attribute__((ext_vector_type(4))) float  f32x4;

#define GLD16(gptr, lptr) __builtin_amdgcn_global_load_lds( \
    (const __attribute__((address_space(1))) void*)(gptr),  \
    (__attribute__((address_space(3))) void*)(lptr), 16, 0, 0)

__device__ __forceinline__ unsigned short f2bf(float v) {
    unsigned int u = __float_as_uint(v);
    u += 0x7fffu + ((u >> 16) & 1u);   // RNE
    return (unsigned short)(u >> 16);
}

// Fused: img -> bf16 (pre-scaled by logit_scale*log2e), txt -> bf16,
// and exact fp32 diag[i] = scale * dot(img[i], txt[i]).
__global__ void preprocess_kernel(const float* __restrict__ img,
                                  const float* __restrict__ txt,
                                  const float* __restrict__ scale_p,
                                  short* __restrict__ imgbf,
                                  short* __restrict__ txtbf,
                                  float* __restrict__ diag) {
    const int row = blockIdx.x;
    const int tid = threadIdx.x;
    const float sc = *scale_p;
    const float f  = sc * 1.44269504088896340736f;

    const float4 x = ((const float4*)(img + (size_t)row * D_DIM))[tid];
    const float4 y = ((const float4*)(txt + (size_t)row * D_DIM))[tid];

    short4 oi, ot;
    oi.x = (short)f2bf(x.x * f); oi.y = (short)f2bf(x.y * f);
    oi.z = (short)f2bf(x.z * f); oi.w = (short)f2bf(x.w * f);
    ot.x = (short)f2bf(y.x);     ot.y = (short)f2bf(y.y);
    ot.z = (short)f2bf(y.z);     ot.w = (short)f2bf(y.w);
    ((short4*)(imgbf + (size_t)row * D_DIM))[tid] = oi;
    ((short4*)(txtbf + (size_t)row * D_DIM))[tid] = ot;

    float s = x.x * y.x + x.y * y.y + x.z * y.z + x.w * y.w;
#pragma unroll
    for (int m = 1; m < 64; m <<= 1) s += __shfl_xor(s, m);
    __shared__ float ws[4];
    if ((tid & 63) == 0) ws[tid >> 6] = s;
    __syncthreads();
    if (tid == 0) diag[row] = (ws[0] + ws[1] + ws[2] + ws[3]) * sc;
}

// 256x256 tile, 8 waves (2M x 4N), pipelined in K-half units (32 cols).
// Ring of 4 slots per matrix; prefetch distance 3 units; vmcnt(8) once
// per unit (never 0). Swizzle: chunk c of row r stored at c ^ ((r>>1)&3)
// -> conflict-free ds_read_b128 under 8-lane service groups.
__global__ __launch_bounds__(512, 2)
void gemm_exp_kernel(const short* __restrict__ A,   // img bf16, scaled
                     const short* __restrict__ B,   // txt bf16
                     float* __restrict__ row_sum,
                     float* __restrict__ col_sum) {
    __shared__ __align__(16) short As[4][SLOT];
    __shared__ __align__(16) short Bs[4][SLOT];

    const int tid  = threadIdx.x;
    const int lane = tid & 63;
    const int w    = tid >> 6;      // wave 0..7
    const int wm   = w >> 2;        // 0..1
    const int wn   = w & 3;         // 0..3
    const int ti   = blockIdx.y * 256;
    const int tj   = blockIdx.x * 256;
    const int quad = lane >> 4;
    const int l15  = lane & 15;

    // ---- staging: dest chunk = i*512 + tid; row r = chunk>>2, pos p = chunk&3
    //      fetched global k-chunk c = p ^ ((r>>1)&3)  (inverse of read swizzle)
    const int r0 = tid >> 2;
    const int c0 = (tid & 3) ^ ((r0 >> 1) & 3);
    const size_t ga0 = (size_t)(ti + r0) * D_DIM + c0 * 8;
    const size_t ga1 = ga0 + (size_t)128 * D_DIM;       // chunk 512+tid: row+128, same c
    const size_t gb0 = (size_t)(tj + r0) * D_DIM + c0 * 8;
    const size_t gb1 = gb0 + (size_t)128 * D_DIM;
    const int dst0 = tid * 8;                            // shorts (lane-linear per wave)
    const int dst1 = 4096 + tid * 8;

    // ---- fragment read addresses: pos = quad ^ ((l15>>1)&3), row-base independent
    const int fq    = quad ^ ((l15 >> 1) & 3);
    const int aoff  = (wm * 128 + l15) * KH + fq * 8;
    const int boff  = (wn * 64  + l15) * KH + fq * 8;

    f32x4 acc[8][4];
#pragma unroll
    for (int i = 0; i < 8; i++)
#pragma unroll
        for (int j = 0; j < 4; j++) acc[i][j] = (f32x4){0.f, 0.f, 0.f, 0.f};

    // ---- prologue: issue units 0,1,2 (12 loads); wait for unit 0 ----
#pragma unroll
    for (int v = 0; v < 3; ++v) {
        const size_t kg = (size_t)v * KH;
        GLD16(A + ga0 + kg, &As[v][dst0]);
        GLD16(A + ga1 + kg, &As[v][dst1]);
        GLD16(B + gb0 + kg, &Bs[v][dst0]);
        GLD16(B + gb1 + kg, &Bs[v][dst1]);
    }
    asm volatile("s_waitcnt vmcnt(8)" ::: "memory");
    __builtin_amdgcn_s_barrier();

    // ---- main loop: 2 phases per unit, 16 MFMA each ----
    for (int u = 0; u < NU; ++u) {
        const short* as = As[u & 3];
        const short* bs = Bs[u & 3];
        const int v     = (u + 3 < NU) ? (u + 3) : (NU - 1);  // idempotent tail re-issue
        const size_t kg = (size_t)v * KH;
        short* adst = As[v & 3];
        short* bdst = Bs[v & 3];

        bf16x8 af[4], bfr[4];

        // ---- phase A: frags fr0-3 x fc0-3; prefetch A(u+3) ----
#pragma unroll
        for (int fc = 0; fc < 4; ++fc) bfr[fc] = *(const bf16x8*)(bs + boff + fc * 512);
#pragma unroll
        for (int fr = 0; fr < 4; ++fr) af[fr]  = *(const bf16x8*)(as + aoff + fr * 512);
        GLD16(A + ga0 + kg, adst + dst0);
        GLD16(A + ga1 + kg, adst + dst1);
        __builtin_amdgcn_s_barrier();
        __builtin_amdgcn_s_setprio(1);
#pragma unroll
        for (int fr = 0; fr < 4; ++fr)
#pragma unroll
            for (int fc = 0; fc < 4; ++fc)
                acc[fr][fc] = __builtin_amdgcn_mfma_f32_16x16x32_bf16(
                    af[fr], bfr[fc], acc[fr][fc], 0, 0, 0);
        __builtin_amdgcn_s_setprio(0);
        __builtin_amdgcn_s_barrier();

        // ---- phase B: frags fr4-7 (B reused); prefetch B(u+3) ----
#pragma unroll
        for (int fr = 0; fr < 4; ++fr)
            af[fr] = *(const bf16x8*)(as + aoff + 2048 + fr * 512);
        GLD16(B + gb0 + kg, bdst + dst0);
        GLD16(B + gb1 + kg, bdst + dst1);
        __builtin_amdgcn_s_barrier();
        __builtin_amdgcn_s_setprio(1);
#pragma unroll
        for (int fr = 0; fr < 4; ++fr)
#pragma unroll
            for (int fc = 0; fc < 4; ++fc)
                acc[4 + fr][fc] = __builtin_amdgcn_mfma_f32_16x16x32_bf16(
                    af[fr], bfr[fc], acc[4 + fr][fc], 0, 0, 0);
        __builtin_amdgcn_s_setprio(0);
        // counted wait: 8 newest (units u+2,u+3) may stay in flight; u+1 landed
        asm volatile("s_waitcnt vmcnt(8)" ::: "memory");
        __builtin_amdgcn_s_barrier();
    }

    // ---- epilogue: e = 2^acc, row/col reductions ----
#pragma unroll
    for (int fr = 0; fr < 8; ++fr)
#pragma unroll
        for (int fc = 0; fc < 4; ++fc)
#pragma unroll
            for (int r = 0; r < 4; ++r)
                acc[fr][fc][r] = __builtin_amdgcn_exp2f(acc[fr][fc][r]);

    // element (fr,fc,r) = logits[ti + wm*128 + fr*16 + quad*4 + r][tj + wn*64 + fc*16 + l15]
    const int rowbase = ti + wm * 128;
#pragma unroll
    for (int fr = 0; fr < 8; ++fr) {
#pragma unroll
        for (int r = 0; r < 4; ++r) {
            float s = acc[fr][0][r] + acc[fr][1][r] + acc[fr][2][r] + acc[fr][3][r];
            s += __shfl_xor(s, 1);
            s += __shfl_xor(s, 2);
            s += __shfl_xor(s, 4);
            s += __shfl_xor(s, 8);
            if (l15 == 0)
                atomicAdd(&row_sum[rowbase + fr * 16 + quad * 4 + r], s);
        }
    }

    const int colbase = tj + wn * 64;
#pragma unroll
    for (int fc = 0; fc < 4; ++fc) {
        float s = 0.f;
#pragma unroll
        for (int fr = 0; fr < 8; ++fr)
#pragma unroll
            for (int r = 0; r < 4; ++r) s += acc[fr][fc][r];
        s += __shfl_xor(s, 16);
        s += __shfl_xor(s, 32);
        if (quad == 0)
            atomicAdd(&col_sum[colbase + fc * 16 + l15], s);
    }
}

__global__ void finish_kernel(const float* __restrict__ rs, const float* __restrict__ cs,
                              const float* __restrict__ diag, float* __restrict__ out) {
    const int tid  = threadIdx.x;
    const int lane = tid & 63;
    const int w    = tid >> 6;
    float s = 0.f;
    for (int i = tid; i < N_ROWS; i += 256)
        s += logf(rs[i]) + logf(cs[i]) - 2.0f * diag[i];
#pragma unroll
    for (int m = 1; m < 64; m <<= 1) s += __shfl_xor(s, m);
    __shared__ float wsum[4];
    if (lane == 0) wsum[w] = s;
    __syncthreads();
    if (tid == 0)
        out[0] = (wsum[0] + wsum[1] + wsum[2] + wsum[3]) * (0.5f / (float)N_ROWS);
}

extern "C" void kernel_launch(void* const* d_in, const int* in_sizes, int n_in,
                              void* d_out, int out_size, void* d_ws, size_t ws_size,
                              hipStream_t stream) {
    const float* img     = (const float*)d_in[0];
    const float* txt     = (const float*)d_in[1];
    const float* scale_p = (const float*)d_in[2];
    float* out = (float*)d_out;

    char* ws = (char*)d_ws;
    short* imgbf   = (short*)ws;                                  // 16 MB
    short* txtbf   = (short*)(ws + (size_t)16 * 1024 * 1024);     // 16 MB
    float* row_sum = (float*)(ws + (size_t)32 * 1024 * 1024);     // 32 KB
    float* col_sum = row_sum + N_ROWS;                            // 32 KB
    float* diag    = col_sum + N_ROWS;                            // 32 KB

    hipMemsetAsync(row_sum, 0, 2 * N_ROWS * sizeof(float), stream);

    preprocess_kernel<<<N_ROWS, 256, 0, stream>>>(img, txt, scale_p, imgbf, txtbf, diag);

    dim3 grid(N_ROWS / 256, N_ROWS / 256);
    gemm_exp_kernel<<<grid, 512, 0, stream>>>(imgbf, txtbf, row_sum, col_sum);

    finish_kernel<<<1, 256, 0, stream>>>(row_sum, col_sum, diag, out);
}

// Round 3
// 290.013 us; speedup vs baseline: 1.1537x; 1.1261x over previous
//
#include <hip/hip_runtime.h>
#include <stdint.h>

#define N_ROWS 8192
#define D_DIM  1024
#define KH     32                 // K-half (pipeline unit) width
#define NU     (D_DIM / KH)       // 32 units
#define SLOT   (256 * KH)         // 8192 shorts = 16 KiB per slot

typedef __attribute__((ext_vector_type(8))) __bf16 bf16x8;
typedef __attribute__((ext_vector_type(4))) float  f32x4;
typedef __attribute__((address_space(3))) short*  lds_sp;

#define GLD16(gptr, lptr) __builtin_amdgcn_global_load_lds( \
    (const __attribute__((address_space(1))) void*)(gptr),  \
    (__attribute__((address_space(3))) void*)(lptr), 16, 0, 0)

// Opaque LDS read: backend waitcnt pass can't see it -> no auto vmcnt/lgkm
// waits; volatile keeps program order vs. our waitcnt asm / GLD16 / barriers.
#define DSR(dst, addr, OFFSTR) \
    asm volatile("ds_read_b128 %0, %1 offset:" OFFSTR : "=v"(dst) : "v"(addr))

__device__ __forceinline__ unsigned short f2bf(float v) {
    unsigned int u = __float_as_uint(v);
    u += 0x7fffu + ((u >> 16) & 1u);   // RNE
    return (unsigned short)(u >> 16);
}

// Fused: img -> bf16 (pre-scaled by logit_scale*log2e), txt -> bf16,
// and exact fp32 diag[i] = scale * dot(img[i], txt[i]).
__global__ void preprocess_kernel(const float* __restrict__ img,
                                  const float* __restrict__ txt,
                                  const float* __restrict__ scale_p,
                                  short* __restrict__ imgbf,
                                  short* __restrict__ txtbf,
                                  float* __restrict__ diag) {
    const int row = blockIdx.x;
    const int tid = threadIdx.x;
    const float sc = *scale_p;
    const float f  = sc * 1.44269504088896340736f;

    const float4 x = ((const float4*)(img + (size_t)row * D_DIM))[tid];
    const float4 y = ((const float4*)(txt + (size_t)row * D_DIM))[tid];

    short4 oi, ot;
    oi.x = (short)f2bf(x.x * f); oi.y = (short)f2bf(x.y * f);
    oi.z = (short)f2bf(x.z * f); oi.w = (short)f2bf(x.w * f);
    ot.x = (short)f2bf(y.x);     ot.y = (short)f2bf(y.y);
    ot.z = (short)f2bf(y.z);     ot.w = (short)f2bf(y.w);
    ((short4*)(imgbf + (size_t)row * D_DIM))[tid] = oi;
    ((short4*)(txtbf + (size_t)row * D_DIM))[tid] = ot;

    float s = x.x * y.x + x.y * y.y + x.z * y.z + x.w * y.w;
#pragma unroll
    for (int m = 1; m < 64; m <<= 1) s += __shfl_xor(s, m);
    __shared__ float ws[4];
    if ((tid & 63) == 0) ws[tid >> 6] = s;
    __syncthreads();
    if (tid == 0) diag[row] = (ws[0] + ws[1] + ws[2] + ws[3]) * sc;
}

// 256x256 tile, 8 waves (2M x 4N), pipelined in K-half units (32 cols).
// Ring of 4 slots/matrix; prefetch distance 3 units; ONE vmcnt(8)/unit.
// All LDS frag reads via opaque inline-asm ds_read_b128 so the compiler
// inserts no waitcnts of its own; explicit lgkmcnt(0)+sched_barrier(0)
// before each MFMA cluster (rule: MFMA hoists past asm waits otherwise).
__global__ __launch_bounds__(512, 2)
void gemm_exp_kernel(const short* __restrict__ A,   // img bf16, scaled
                     const short* __restrict__ B,   // txt bf16
                     float* __restrict__ row_sum,
                     float* __restrict__ col_sum) {
    __shared__ __align__(16) short As[4][SLOT];
    __shared__ __align__(16) short Bs[4][SLOT];

    const int tid  = threadIdx.x;
    const int lane = tid & 63;
    const int w    = tid >> 6;      // wave 0..7
    const int wm   = w >> 2;        // 0..1
    const int wn   = w & 3;         // 0..3
    const int ti   = blockIdx.y * 256;
    const int tj   = blockIdx.x * 256;
    const int quad = lane >> 4;
    const int l15  = lane & 15;

    // ---- staging: dest chunk = i*512 + tid; row r = chunk>>2, pos p = chunk&3
    //      fetched global k-chunk c = p ^ ((r>>1)&3)  (inverse of read swizzle)
    const int r0 = tid >> 2;
    const int c0 = (tid & 3) ^ ((r0 >> 1) & 3);
    const size_t ga0 = (size_t)(ti + r0) * D_DIM + c0 * 8;
    const size_t ga1 = ga0 + (size_t)128 * D_DIM;
    const size_t gb0 = (size_t)(tj + r0) * D_DIM + c0 * 8;
    const size_t gb1 = gb0 + (size_t)128 * D_DIM;
    const int dst0 = tid * 8;                            // shorts
    const int dst1 = 4096 + tid * 8;

    // ---- fragment LDS byte addresses (swizzled pos = quad ^ ((l15>>1)&3)) ----
    const int fq = quad ^ ((l15 >> 1) & 3);
    const uint32_t ldsA0 = (uint32_t)(uintptr_t)(lds_sp)&As[0][0];
    const uint32_t ldsB0 = (uint32_t)(uintptr_t)(lds_sp)&Bs[0][0];
    const uint32_t aoffB = (uint32_t)(((wm * 128 + l15) * KH + fq * 8) * 2);
    const uint32_t boffB = (uint32_t)(((wn * 64  + l15) * KH + fq * 8) * 2);

    f32x4 acc[8][4];
#pragma unroll
    for (int i = 0; i < 8; i++)
#pragma unroll
        for (int j = 0; j < 4; j++) acc[i][j] = (f32x4){0.f, 0.f, 0.f, 0.f};

    // ---- prologue: issue units 0,1,2 (12 loads); wait for unit 0 ----
#pragma unroll
    for (int v = 0; v < 3; ++v) {
        const size_t kg = (size_t)v * KH;
        GLD16(A + ga0 + kg, &As[v][dst0]);
        GLD16(A + ga1 + kg, &As[v][dst1]);
        GLD16(B + gb0 + kg, &Bs[v][dst0]);
        GLD16(B + gb1 + kg, &Bs[v][dst1]);
    }
    asm volatile("s_waitcnt vmcnt(8)" ::: "memory");
    __builtin_amdgcn_s_barrier();
    __builtin_amdgcn_sched_barrier(0);

    // ---- main loop: 2 phases per unit, 16 MFMA each ----
    for (int u = 0; u < NU; ++u) {
        const uint32_t sb = (uint32_t)(u & 3) * (SLOT * 2);
        const uint32_t aA = ldsA0 + sb + aoffB;
        const uint32_t aB = ldsB0 + sb + boffB;
        const int v     = (u + 3 < NU) ? (u + 3) : (NU - 1);  // idempotent tail
        const size_t kg = (size_t)v * KH;
        short* adst = As[v & 3];
        short* bdst = Bs[v & 3];

        bf16x8 af[4], bfr[4];

        // ---- phase A: stage A(u+3); frags fr0-3 x fc0-3 ----
        GLD16(A + ga0 + kg, adst + dst0);
        GLD16(A + ga1 + kg, adst + dst1);
        DSR(bfr[0], aB, "0");    DSR(bfr[1], aB, "1024");
        DSR(bfr[2], aB, "2048"); DSR(bfr[3], aB, "3072");
        DSR(af[0], aA, "0");     DSR(af[1], aA, "1024");
        DSR(af[2], aA, "2048");  DSR(af[3], aA, "3072");
        __builtin_amdgcn_s_barrier();
        asm volatile("s_waitcnt lgkmcnt(0)" ::: "memory");
        __builtin_amdgcn_sched_barrier(0);
        __builtin_amdgcn_s_setprio(1);
#pragma unroll
        for (int fr = 0; fr < 4; ++fr)
#pragma unroll
            for (int fc = 0; fc < 4; ++fc)
                acc[fr][fc] = __builtin_amdgcn_mfma_f32_16x16x32_bf16(
                    af[fr], bfr[fc], acc[fr][fc], 0, 0, 0);
        __builtin_amdgcn_s_setprio(0);
        __builtin_amdgcn_s_barrier();

        // ---- phase B: stage B(u+3); frags fr4-7 (B reused) ----
        GLD16(B + gb0 + kg, bdst + dst0);
        GLD16(B + gb1 + kg, bdst + dst1);
        DSR(af[0], aA, "4096");  DSR(af[1], aA, "5120");
        DSR(af[2], aA, "6144");  DSR(af[3], aA, "7168");
        __builtin_amdgcn_s_barrier();
        asm volatile("s_waitcnt lgkmcnt(0)" ::: "memory");
        __builtin_amdgcn_sched_barrier(0);
        __builtin_amdgcn_s_setprio(1);
#pragma unroll
        for (int fr = 0; fr < 4; ++fr)
#pragma unroll
            for (int fc = 0; fc < 4; ++fc)
                acc[4 + fr][fc] = __builtin_amdgcn_mfma_f32_16x16x32_bf16(
                    af[fr], bfr[fc], acc[4 + fr][fc], 0, 0, 0);
        __builtin_amdgcn_s_setprio(0);
        // counted wait: units u+2,u+3 (8 loads) stay in flight; u+1 landed
        asm volatile("s_waitcnt vmcnt(8)" ::: "memory");
        __builtin_amdgcn_s_barrier();
    }

    // ---- epilogue: e = 2^acc, row/col reductions ----
#pragma unroll
    for (int fr = 0; fr < 8; ++fr)
#pragma unroll
        for (int fc = 0; fc < 4; ++fc)
#pragma unroll
            for (int r = 0; r < 4; ++r)
                acc[fr][fc][r] = __builtin_amdgcn_exp2f(acc[fr][fc][r]);

    // element (fr,fc,r) = logits[ti + wm*128 + fr*16 + quad*4 + r][tj + wn*64 + fc*16 + l15]
    const int rowbase = ti + wm * 128;
#pragma unroll
    for (int fr = 0; fr < 8; ++fr) {
#pragma unroll
        for (int r = 0; r < 4; ++r) {
            float s = acc[fr][0][r] + acc[fr][1][r] + acc[fr][2][r] + acc[fr][3][r];
            s += __shfl_xor(s, 1);
            s += __shfl_xor(s, 2);
            s += __shfl_xor(s, 4);
            s += __shfl_xor(s, 8);
            if (l15 == 0)
                atomicAdd(&row_sum[rowbase + fr * 16 + quad * 4 + r], s);
        }
    }

    const int colbase = tj + wn * 64;
#pragma unroll
    for (int fc = 0; fc < 4; ++fc) {
        float s = 0.f;
#pragma unroll
        for (int fr = 0; fr < 8; ++fr)
#pragma unroll
            for (int r = 0; r < 4; ++r) s += acc[fr][fc][r];
        s += __shfl_xor(s, 16);
        s += __shfl_xor(s, 32);
        if (quad == 0)
            atomicAdd(&col_sum[colbase + fc * 16 + l15], s);
    }
}

__global__ void finish_kernel(const float* __restrict__ rs, const float* __restrict__ cs,
                              const float* __restrict__ diag, float* __restrict__ out) {
    const int tid  = threadIdx.x;
    const int lane = tid & 63;
    const int w    = tid >> 6;
    float s = 0.f;
    for (int i = tid; i < N_ROWS; i += 256)
        s += logf(rs[i]) + logf(cs[i]) - 2.0f * diag[i];
#pragma unroll
    for (int m = 1; m < 64; m <<= 1) s += __shfl_xor(s, m);
    __shared__ float wsum[4];
    if (lane == 0) wsum[w] = s;
    __syncthreads();
    if (tid == 0)
        out[0] = (wsum[0] + wsum[1] + wsum[2] + wsum[3]) * (0.5f / (float)N_ROWS);
}

extern "C" void kernel_launch(void* const* d_in, const int* in_sizes, int n_in,
                              void* d_out, int out_size, void* d_ws, size_t ws_size,
                              hipStream_t stream) {
    const float* img     = (const float*)d_in[0];
    const float* txt     = (const float*)d_in[1];
    const float* scale_p = (const float*)d_in[2];
    float* out = (float*)d_out;

    char* ws = (char*)d_ws;
    short* imgbf   = (short*)ws;                                  // 16 MB
    short* txtbf   = (short*)(ws + (size_t)16 * 1024 * 1024);     // 16 MB
    float* row_sum = (float*)(ws + (size_t)32 * 1024 * 1024);     // 32 KB
    float* col_sum = row_sum + N_ROWS;                            // 32 KB
    float* diag    = col_sum + N_ROWS;                            // 32 KB

    hipMemsetAsync(row_sum, 0, 2 * N_ROWS * sizeof(float), stream);

    preprocess_kernel<<<N_ROWS, 256, 0, stream>>>(img, txt, scale_p, imgbf, txtbf, diag);

    dim3 grid(N_ROWS / 256, N_ROWS / 256);
    gemm_exp_kernel<<<grid, 512, 0, stream>>>(imgbf, txtbf, row_sum, col_sum);

    finish_kernel<<<1, 256, 0, stream>>>(row_sum, col_sum, diag, out);
}

// Round 4
// 288.684 us; speedup vs baseline: 1.1590x; 1.0046x over previous
//
#include <hip/hip_runtime.h>
#include <stdint.h>

#define N_ROWS 8192
#define D_DIM  1024
#define KH     32                 // K-half (pipeline unit) width
#define NU     (D_DIM / KH)       // 32 units
#define SLOT   (256 * KH)         // 8192 shorts = 16 KiB per slot

typedef __attribute__((ext_vector_type(8))) __bf16 bf16x8;
typedef __attribute__((ext_vector_type(4))) float  f32x4;
typedef __attribute__((address_space(3))) short*  lds_sp;

#define GLD16(gptr, lptr) __builtin_amdgcn_global_load_lds( \
    (const __attribute__((address_space(1))) void*)(gptr),  \
    (__attribute__((address_space(3))) void*)(lptr), 16, 0, 0)

// Opaque LDS read: backend waitcnt pass can't see it -> no auto vmcnt/lgkm
// waits; volatile keeps program order vs. our waitcnt asm / GLD16 / barriers.
#define DSR(dst, addr, OFFSTR) \
    asm volatile("ds_read_b128 %0, %1 offset:" OFFSTR : "=v"(dst) : "v"(addr))

__device__ __forceinline__ unsigned short f2bf(float v) {
    unsigned int u = __float_as_uint(v);
    u += 0x7fffu + ((u >> 16) & 1u);   // RNE
    return (unsigned short)(u >> 16);
}

// Fused: img -> bf16 (pre-scaled by logit_scale*log2e), txt -> bf16,
// exact fp32 diag, and zeroing of row/col accumulators (replaces memset).
__global__ void preprocess_kernel(const float* __restrict__ img,
                                  const float* __restrict__ txt,
                                  const float* __restrict__ scale_p,
                                  short* __restrict__ imgbf,
                                  short* __restrict__ txtbf,
                                  float* __restrict__ diag,
                                  float* __restrict__ row_sum,
                                  float* __restrict__ col_sum) {
    const int row = blockIdx.x;
    const int tid = threadIdx.x;
    const float sc = *scale_p;
    const float f  = sc * 1.44269504088896340736f;

    const float4 x = ((const float4*)(img + (size_t)row * D_DIM))[tid];
    const float4 y = ((const float4*)(txt + (size_t)row * D_DIM))[tid];

    short4 oi, ot;
    oi.x = (short)f2bf(x.x * f); oi.y = (short)f2bf(x.y * f);
    oi.z = (short)f2bf(x.z * f); oi.w = (short)f2bf(x.w * f);
    ot.x = (short)f2bf(y.x);     ot.y = (short)f2bf(y.y);
    ot.z = (short)f2bf(y.z);     ot.w = (short)f2bf(y.w);
    ((short4*)(imgbf + (size_t)row * D_DIM))[tid] = oi;
    ((short4*)(txtbf + (size_t)row * D_DIM))[tid] = ot;

    float s = x.x * y.x + x.y * y.y + x.z * y.z + x.w * y.w;
#pragma unroll
    for (int m = 1; m < 64; m <<= 1) s += __shfl_xor(s, m);
    __shared__ float ws[4];
    if ((tid & 63) == 0) ws[tid >> 6] = s;
    __syncthreads();
    if (tid == 0) {
        diag[row]    = (ws[0] + ws[1] + ws[2] + ws[3]) * sc;
        row_sum[row] = 0.f;
        col_sum[row] = 0.f;
    }
}

// 256x256 tile, 8 waves (2M x 4N), pipelined in K-half units (32 cols).
// Ring of 4 slots/matrix; prefetch distance 3; ONE barrier + ONE vmcnt(8)
// per unit. Per unit: issue 4 GLD16, 12 opaque ds_read_b128, then
// lgkmcnt(4) -> 16 MFMA -> lgkmcnt(0) -> 16 MFMA. Mid-unit barriers
// removed: both MFMA clusters read only slot u (safe since barrier u-1),
// GLD16s write slot (u+3)&3 which is read no earlier than unit u+3.
__global__ __launch_bounds__(512, 2)
void gemm_exp_kernel(const short* __restrict__ A,   // img bf16, scaled
                     const short* __restrict__ B,   // txt bf16
                     float* __restrict__ row_sum,
                     float* __restrict__ col_sum) {
    __shared__ __align__(16) short As[4][SLOT];
    __shared__ __align__(16) short Bs[4][SLOT];

    const int tid  = threadIdx.x;
    const int lane = tid & 63;
    const int w    = tid >> 6;      // wave 0..7
    const int wm   = w >> 2;        // 0..1
    const int wn   = w & 3;         // 0..3
    const int ti   = blockIdx.y * 256;
    const int tj   = blockIdx.x * 256;
    const int quad = lane >> 4;
    const int l15  = lane & 15;

    // ---- staging: dest chunk = i*512 + tid; row r = chunk>>2, pos p = chunk&3
    //      fetched global k-chunk c = p ^ ((r>>1)&3)  (inverse of read swizzle)
    const int r0 = tid >> 2;
    const int c0 = (tid & 3) ^ ((r0 >> 1) & 3);
    const size_t ga0 = (size_t)(ti + r0) * D_DIM + c0 * 8;
    const size_t ga1 = ga0 + (size_t)128 * D_DIM;
    const size_t gb0 = (size_t)(tj + r0) * D_DIM + c0 * 8;
    const size_t gb1 = gb0 + (size_t)128 * D_DIM;
    const int dst0 = tid * 8;                            // shorts
    const int dst1 = 4096 + tid * 8;

    // ---- fragment LDS byte addresses (swizzled pos = quad ^ ((l15>>1)&3)) ----
    const int fq = quad ^ ((l15 >> 1) & 3);
    const uint32_t ldsA0 = (uint32_t)(uintptr_t)(lds_sp)&As[0][0];
    const uint32_t ldsB0 = (uint32_t)(uintptr_t)(lds_sp)&Bs[0][0];
    const uint32_t aoffB = (uint32_t)(((wm * 128 + l15) * KH + fq * 8) * 2);
    const uint32_t boffB = (uint32_t)(((wn * 64  + l15) * KH + fq * 8) * 2);

    f32x4 acc[8][4];
#pragma unroll
    for (int i = 0; i < 8; i++)
#pragma unroll
        for (int j = 0; j < 4; j++) acc[i][j] = (f32x4){0.f, 0.f, 0.f, 0.f};

    // ---- prologue: issue units 0,1,2 (12 loads); wait for unit 0 ----
#pragma unroll
    for (int v = 0; v < 3; ++v) {
        const size_t kg = (size_t)v * KH;
        GLD16(A + ga0 + kg, &As[v][dst0]);
        GLD16(A + ga1 + kg, &As[v][dst1]);
        GLD16(B + gb0 + kg, &Bs[v][dst0]);
        GLD16(B + gb1 + kg, &Bs[v][dst1]);
    }
    asm volatile("s_waitcnt vmcnt(8)" ::: "memory");
    __builtin_amdgcn_s_barrier();
    __builtin_amdgcn_sched_barrier(0);

    // ---- main loop: one fused unit, 2 MFMA clusters, counted lgkm ----
    for (int u = 0; u < NU; ++u) {
        const uint32_t sb = (uint32_t)(u & 3) * (SLOT * 2);
        const uint32_t aA = ldsA0 + sb + aoffB;
        const uint32_t aB = ldsB0 + sb + boffB;
        const int v     = (u + 3 < NU) ? (u + 3) : (NU - 1);  // idempotent tail
        const size_t kg = (size_t)v * KH;
        short* adst = As[v & 3];
        short* bdst = Bs[v & 3];

        // prefetch unit u+3 (4 VMEM issues; latency hides under 2 clusters)
        GLD16(A + ga0 + kg, adst + dst0);
        GLD16(A + ga1 + kg, adst + dst1);
        GLD16(B + gb0 + kg, bdst + dst0);
        GLD16(B + gb1 + kg, bdst + dst1);

        bf16x8 af[8], bfr[4];
        DSR(bfr[0], aB, "0");    DSR(bfr[1], aB, "1024");
        DSR(bfr[2], aB, "2048"); DSR(bfr[3], aB, "3072");
        DSR(af[0], aA, "0");     DSR(af[1], aA, "1024");
        DSR(af[2], aA, "2048");  DSR(af[3], aA, "3072");
        DSR(af[4], aA, "4096");  DSR(af[5], aA, "5120");
        DSR(af[6], aA, "6144");  DSR(af[7], aA, "7168");

        // first 8 DS ops (bfr + af[0..3]) complete; af[4..7] still in flight
        asm volatile("s_waitcnt lgkmcnt(4)" ::: "memory");
        __builtin_amdgcn_sched_barrier(0);
        __builtin_amdgcn_s_setprio(1);
#pragma unroll
        for (int fr = 0; fr < 4; ++fr)
#pragma unroll
            for (int fc = 0; fc < 4; ++fc)
                acc[fr][fc] = __builtin_amdgcn_mfma_f32_16x16x32_bf16(
                    af[fr], bfr[fc], acc[fr][fc], 0, 0, 0);
        __builtin_amdgcn_s_setprio(0);

        asm volatile("s_waitcnt lgkmcnt(0)" ::: "memory");
        __builtin_amdgcn_sched_barrier(0);
        __builtin_amdgcn_s_setprio(1);
#pragma unroll
        for (int fr = 0; fr < 4; ++fr)
#pragma unroll
            for (int fc = 0; fc < 4; ++fc)
                acc[4 + fr][fc] = __builtin_amdgcn_mfma_f32_16x16x32_bf16(
                    af[4 + fr], bfr[fc], acc[4 + fr][fc], 0, 0, 0);
        __builtin_amdgcn_s_setprio(0);

        // counted wait: units u+2,u+3 (8 loads) stay in flight; u+1 landed
        asm volatile("s_waitcnt vmcnt(8)" ::: "memory");
        __builtin_amdgcn_s_barrier();
    }

    // ---- epilogue: e = 2^acc, row/col reductions ----
#pragma unroll
    for (int fr = 0; fr < 8; ++fr)
#pragma unroll
        for (int fc = 0; fc < 4; ++fc)
#pragma unroll
            for (int r = 0; r < 4; ++r)
                acc[fr][fc][r] = __builtin_amdgcn_exp2f(acc[fr][fc][r]);

    // element (fr,fc,r) = logits[ti + wm*128 + fr*16 + quad*4 + r][tj + wn*64 + fc*16 + l15]
    const int rowbase = ti + wm * 128;
#pragma unroll
    for (int fr = 0; fr < 8; ++fr) {
#pragma unroll
        for (int r = 0; r < 4; ++r) {
            float s = acc[fr][0][r] + acc[fr][1][r] + acc[fr][2][r] + acc[fr][3][r];
            s += __shfl_xor(s, 1);
            s += __shfl_xor(s, 2);
            s += __shfl_xor(s, 4);
            s += __shfl_xor(s, 8);
            if (l15 == 0)
                atomicAdd(&row_sum[rowbase + fr * 16 + quad * 4 + r], s);
        }
    }

    const int colbase = tj + wn * 64;
#pragma unroll
    for (int fc = 0; fc < 4; ++fc) {
        float s = 0.f;
#pragma unroll
        for (int fr = 0; fr < 8; ++fr)
#pragma unroll
            for (int r = 0; r < 4; ++r) s += acc[fr][fc][r];
        s += __shfl_xor(s, 16);
        s += __shfl_xor(s, 32);
        if (quad == 0)
            atomicAdd(&col_sum[colbase + fc * 16 + l15], s);
    }
}

__global__ void finish_kernel(const float* __restrict__ rs, const float* __restrict__ cs,
                              const float* __restrict__ diag, float* __restrict__ out) {
    const int tid  = threadIdx.x;
    const int lane = tid & 63;
    const int w    = tid >> 6;
    float s = 0.f;
    for (int i = tid; i < N_ROWS; i += 256)
        s += logf(rs[i]) + logf(cs[i]) - 2.0f * diag[i];
#pragma unroll
    for (int m = 1; m < 64; m <<= 1) s += __shfl_xor(s, m);
    __shared__ float wsum[4];
    if (lane == 0) wsum[w] = s;
    __syncthreads();
    if (tid == 0)
        out[0] = (wsum[0] + wsum[1] + wsum[2] + wsum[3]) * (0.5f / (float)N_ROWS);
}

extern "C" void kernel_launch(void* const* d_in, const int* in_sizes, int n_in,
                              void* d_out, int out_size, void* d_ws, size_t ws_size,
                              hipStream_t stream) {
    const float* img     = (const float*)d_in[0];
    const float* txt     = (const float*)d_in[1];
    const float* scale_p = (const float*)d_in[2];
    float* out = (float*)d_out;

    char* ws = (char*)d_ws;
    short* imgbf   = (short*)ws;                                  // 16 MB
    short* txtbf   = (short*)(ws + (size_t)16 * 1024 * 1024);     // 16 MB
    float* row_sum = (float*)(ws + (size_t)32 * 1024 * 1024);     // 32 KB
    float* col_sum = row_sum + N_ROWS;                            // 32 KB
    float* diag    = col_sum + N_ROWS;                            // 32 KB

    preprocess_kernel<<<N_ROWS, 256, 0, stream>>>(img, txt, scale_p, imgbf, txtbf,
                                                  diag, row_sum, col_sum);

    dim3 grid(N_ROWS / 256, N_ROWS / 256);
    gemm_exp_kernel<<<grid, 512, 0, stream>>>(imgbf, txtbf, row_sum, col_sum);

    finish_kernel<<<1, 256, 0, stream>>>(row_sum, col_sum, diag, out);
}

// Round 5
// 285.790 us; speedup vs baseline: 1.1707x; 1.0101x over previous
//
#include <hip/hip_runtime.h>
#include <stdint.h>

#define N_ROWS 8192
#define D_DIM  1024
#define KH     32                 // K-half (pipeline unit) width
#define NU     (D_DIM / KH)       // 32 units
#define SLOT   (256 * KH)         // 8192 shorts = 16 KiB per slot

typedef __attribute__((ext_vector_type(8))) __bf16 bf16x8;
typedef __attribute__((ext_vector_type(4))) float  f32x4;
typedef __attribute__((address_space(3))) short*  lds_sp;

#define GLD16(gptr, lptr) __builtin_amdgcn_global_load_lds( \
    (const __attribute__((address_space(1))) void*)(gptr),  \
    (__attribute__((address_space(3))) void*)(lptr), 16, 0, 0)

// Opaque LDS read: backend waitcnt pass can't see it -> no auto waits.
#define DSR(dst, addr, OFFSTR) \
    asm volatile("ds_read_b128 %0, %1 offset:" OFFSTR : "=v"(dst) : "v"(addr))

// 12 reads for one unit into a named register set (4 B-frags + 8 A-frags).
#define READ12(af, bf, aA, aB)                              \
    DSR(bf[0], aB, "0");    DSR(bf[1], aB, "1024");         \
    DSR(bf[2], aB, "2048"); DSR(bf[3], aB, "3072");         \
    DSR(af[0], aA, "0");    DSR(af[1], aA, "1024");         \
    DSR(af[2], aA, "2048"); DSR(af[3], aA, "3072");         \
    DSR(af[4], aA, "4096"); DSR(af[5], aA, "5120");         \
    DSR(af[6], aA, "6144"); DSR(af[7], aA, "7168")

#define MFMA32(af, bf)                                              \
    _Pragma("unroll")                                               \
    for (int fr = 0; fr < 8; ++fr) {                                \
        _Pragma("unroll")                                           \
        for (int fc = 0; fc < 4; ++fc)                              \
            acc[fr][fc] = __builtin_amdgcn_mfma_f32_16x16x32_bf16(  \
                af[fr], bf[fc], acc[fr][fc], 0, 0, 0);              \
    }

// One pipeline unit: stage unit w+3 (fixed dest slot), read frags for unit
// w+1 into the OTHER register set (afN/bfN), then MFMA unit w (afC/bfC).
// lgkmcnt(12): the 12 just-issued reads may remain; current unit's retired.
// vmcnt(4): all staging through unit w+2 landed; w+3's 4 loads in flight.
#define UNIT(afC, bfC, afN, bfN, aAn, aBn, SSLOT, KG)               \
    GLD16(pa0 + (KG), &As[SSLOT][dst0]);                            \
    GLD16(pa1 + (KG), &As[SSLOT][dst1]);                            \
    GLD16(pb0 + (KG), &Bs[SSLOT][dst0]);                            \
    GLD16(pb1 + (KG), &Bs[SSLOT][dst1]);                            \
    READ12(afN, bfN, aAn, aBn);                                     \
    asm volatile("s_waitcnt lgkmcnt(12)" ::: "memory");             \
    __builtin_amdgcn_sched_barrier(0);                              \
    __builtin_amdgcn_s_setprio(1);                                  \
    MFMA32(afC, bfC);                                               \
    __builtin_amdgcn_s_setprio(0);                                  \
    __builtin_amdgcn_sched_barrier(0);                              \
    asm volatile("s_waitcnt vmcnt(4)" ::: "memory");                \
    __builtin_amdgcn_s_barrier();

__device__ __forceinline__ unsigned short f2bf(float v) {
    unsigned int u = __float_as_uint(v);
    u += 0x7fffu + ((u >> 16) & 1u);   // RNE
    return (unsigned short)(u >> 16);
}

// Fused: img -> bf16 (pre-scaled by logit_scale*log2e), txt -> bf16,
// exact fp32 diag, and zeroing of row/col accumulators.
__global__ void preprocess_kernel(const float* __restrict__ img,
                                  const float* __restrict__ txt,
                                  const float* __restrict__ scale_p,
                                  short* __restrict__ imgbf,
                                  short* __restrict__ txtbf,
                                  float* __restrict__ diag,
                                  float* __restrict__ row_sum,
                                  float* __restrict__ col_sum) {
    const int row = blockIdx.x;
    const int tid = threadIdx.x;
    const float sc = *scale_p;
    const float f  = sc * 1.44269504088896340736f;

    const float4 x = ((const float4*)(img + (size_t)row * D_DIM))[tid];
    const float4 y = ((const float4*)(txt + (size_t)row * D_DIM))[tid];

    short4 oi, ot;
    oi.x = (short)f2bf(x.x * f); oi.y = (short)f2bf(x.y * f);
    oi.z = (short)f2bf(x.z * f); oi.w = (short)f2bf(x.w * f);
    ot.x = (short)f2bf(y.x);     ot.y = (short)f2bf(y.y);
    ot.z = (short)f2bf(y.z);     ot.w = (short)f2bf(y.w);
    ((short4*)(imgbf + (size_t)row * D_DIM))[tid] = oi;
    ((short4*)(txtbf + (size_t)row * D_DIM))[tid] = ot;

    float s = x.x * y.x + x.y * y.y + x.z * y.z + x.w * y.w;
#pragma unroll
    for (int m = 1; m < 64; m <<= 1) s += __shfl_xor(s, m);
    __shared__ float ws[4];
    if ((tid & 63) == 0) ws[tid >> 6] = s;
    __syncthreads();
    if (tid == 0) {
        diag[row]    = (ws[0] + ws[1] + ws[2] + ws[3]) * sc;
        row_sum[row] = 0.f;
        col_sum[row] = 0.f;
    }
}

// 256x256 tile, 8 waves (2M x 4N), K-half pipeline units, ring-4 slots.
// Register-rotated operand sets (E/O) + lookahead-1 ds_reads break the
// WAR chain between unit u+1's LDS reads and unit u's in-flight MFMAs.
__global__ __launch_bounds__(512, 2)
void gemm_exp_kernel(const short* __restrict__ A,   // img bf16, scaled
                     const short* __restrict__ B,   // txt bf16
                     float* __restrict__ row_sum,
                     float* __restrict__ col_sum) {
    __shared__ __align__(16) short As[4][SLOT];
    __shared__ __align__(16) short Bs[4][SLOT];

    const int tid  = threadIdx.x;
    const int lane = tid & 63;
    const int w    = tid >> 6;      // wave 0..7
    const int wm   = w >> 2;        // 0..1
    const int wn   = w & 3;         // 0..3
    const int ti   = blockIdx.y * 256;
    const int tj   = blockIdx.x * 256;
    const int quad = lane >> 4;
    const int l15  = lane & 15;

    // ---- staging: dest chunk = i*512 + tid; row r = chunk>>2, pos p = chunk&3
    //      fetched global k-chunk c = p ^ ((r>>1)&3)  (inverse of read swizzle)
    const int r0 = tid >> 2;
    const int c0 = (tid & 3) ^ ((r0 >> 1) & 3);
    const short* pa0 = A + (size_t)(ti + r0) * D_DIM + c0 * 8;
    const short* pa1 = pa0 + (size_t)128 * D_DIM;
    const short* pb0 = B + (size_t)(tj + r0) * D_DIM + c0 * 8;
    const short* pb1 = pb0 + (size_t)128 * D_DIM;
    const int dst0 = tid * 8;                            // shorts
    const int dst1 = 4096 + tid * 8;

    // ---- fragment LDS byte addresses (swizzled pos = quad ^ ((l15>>1)&3)) ----
    const int fq = quad ^ ((l15 >> 1) & 3);
    const uint32_t ldsA0 = (uint32_t)(uintptr_t)(lds_sp)&As[0][0];
    const uint32_t ldsB0 = (uint32_t)(uintptr_t)(lds_sp)&Bs[0][0];
    const uint32_t aoffB = (uint32_t)(((wm * 128 + l15) * KH + fq * 8) * 2);
    const uint32_t boffB = (uint32_t)(((wn * 64  + l15) * KH + fq * 8) * 2);
    const uint32_t aA0 = ldsA0 + aoffB,               aB0 = ldsB0 + boffB;
    const uint32_t aA1 = aA0 + 1 * SLOT * 2,          aB1 = aB0 + 1 * SLOT * 2;
    const uint32_t aA2 = aA0 + 2 * SLOT * 2,          aB2 = aB0 + 2 * SLOT * 2;
    const uint32_t aA3 = aA0 + 3 * SLOT * 2,          aB3 = aB0 + 3 * SLOT * 2;

    f32x4 acc[8][4];
#pragma unroll
    for (int i = 0; i < 8; i++)
#pragma unroll
        for (int j = 0; j < 4; j++) acc[i][j] = (f32x4){0.f, 0.f, 0.f, 0.f};

    // ---- prologue: stage units 0,1,2; wait units 0,1; read unit 0 -> E ----
#pragma unroll
    for (int v = 0; v < 3; ++v) {
        const int kg = v * KH;
        GLD16(pa0 + kg, &As[v][dst0]);
        GLD16(pa1 + kg, &As[v][dst1]);
        GLD16(pb0 + kg, &Bs[v][dst0]);
        GLD16(pb1 + kg, &Bs[v][dst1]);
    }
    asm volatile("s_waitcnt vmcnt(4)" ::: "memory");   // units 0,1 landed
    __builtin_amdgcn_s_barrier();
    __builtin_amdgcn_sched_barrier(0);

    bf16x8 afE[8], bfE[4], afO[8], bfO[4];
    READ12(afE, bfE, aA0, aB0);                        // unit 0 frags

    // ---- main loop: quads of 4 units; fixed slots; E/O register rotation.
    // unit 4q+0: MFMA E(slot0), read O<-slot1, stage slot3 (unit 4q+3)
    // unit 4q+1: MFMA O(slot1), read E<-slot2, stage slot0 (unit 4q+4)
    // unit 4q+2: MFMA E(slot2), read O<-slot3, stage slot1 (unit 4q+5)
    // unit 4q+3: MFMA O(slot3), read E<-slot0, stage slot2 (unit 4q+6)
    // Tail: source kg clamps to unit 31 (writes stale slots never read again).
#pragma unroll 1
    for (int q = 0; q < 8; ++q) {
        const int u  = q * 4;
        const int k3 = (u + 3) * KH;                       // always <= 31*KH
        const int k4 = ((u + 4 < NU) ? (u + 4) : (NU - 1)) * KH;
        const int k5 = ((u + 5 < NU) ? (u + 5) : (NU - 1)) * KH;
        const int k6 = ((u + 6 < NU) ? (u + 6) : (NU - 1)) * KH;

        UNIT(afE, bfE, afO, bfO, aA1, aB1, 3, k3)
        UNIT(afO, bfO, afE, bfE, aA2, aB2, 0, k4)
        UNIT(afE, bfE, afO, bfO, aA3, aB3, 1, k5)
        UNIT(afO, bfO, afE, bfE, aA0, aB0, 2, k6)
    }

    // ---- epilogue: e = 2^acc, row/col reductions ----
#pragma unroll
    for (int fr = 0; fr < 8; ++fr)
#pragma unroll
        for (int fc = 0; fc < 4; ++fc)
#pragma unroll
            for (int r = 0; r < 4; ++r)
                acc[fr][fc][r] = __builtin_amdgcn_exp2f(acc[fr][fc][r]);

    // element (fr,fc,r) = logits[ti + wm*128 + fr*16 + quad*4 + r][tj + wn*64 + fc*16 + l15]
    const int rowbase = ti + wm * 128;
#pragma unroll
    for (int fr = 0; fr < 8; ++fr) {
#pragma unroll
        for (int r = 0; r < 4; ++r) {
            float s = acc[fr][0][r] + acc[fr][1][r] + acc[fr][2][r] + acc[fr][3][r];
            s += __shfl_xor(s, 1);
            s += __shfl_xor(s, 2);
            s += __shfl_xor(s, 4);
            s += __shfl_xor(s, 8);
            if (l15 == 0)
                atomicAdd(&row_sum[rowbase + fr * 16 + quad * 4 + r], s);
        }
    }

    const int colbase = tj + wn * 64;
#pragma unroll
    for (int fc = 0; fc < 4; ++fc) {
        float s = 0.f;
#pragma unroll
        for (int fr = 0; fr < 8; ++fr)
#pragma unroll
            for (int r = 0; r < 4; ++r) s += acc[fr][fc][r];
        s += __shfl_xor(s, 16);
        s += __shfl_xor(s, 32);
        if (quad == 0)
            atomicAdd(&col_sum[colbase + fc * 16 + l15], s);
    }
}

__global__ void finish_kernel(const float* __restrict__ rs, const float* __restrict__ cs,
                              const float* __restrict__ diag, float* __restrict__ out) {
    const int tid  = threadIdx.x;
    const int lane = tid & 63;
    const int w    = tid >> 6;
    float s = 0.f;
    for (int i = tid; i < N_ROWS; i += 256)
        s += logf(rs[i]) + logf(cs[i]) - 2.0f * diag[i];
#pragma unroll
    for (int m = 1; m < 64; m <<= 1) s += __shfl_xor(s, m);
    __shared__ float wsum[4];
    if (lane == 0) wsum[w] = s;
    __syncthreads();
    if (tid == 0)
        out[0] = (wsum[0] + wsum[1] + wsum[2] + wsum[3]) * (0.5f / (float)N_ROWS);
}

extern "C" void kernel_launch(void* const* d_in, const int* in_sizes, int n_in,
                              void* d_out, int out_size, void* d_ws, size_t ws_size,
                              hipStream_t stream) {
    const float* img     = (const float*)d_in[0];
    const float* txt     = (const float*)d_in[1];
    const float* scale_p = (const float*)d_in[2];
    float* out = (float*)d_out;

    char* ws = (char*)d_ws;
    short* imgbf   = (short*)ws;                                  // 16 MB
    short* txtbf   = (short*)(ws + (size_t)16 * 1024 * 1024);     // 16 MB
    float* row_sum = (float*)(ws + (size_t)32 * 1024 * 1024);     // 32 KB
    float* col_sum = row_sum + N_ROWS;                            // 32 KB
    float* diag    = col_sum + N_ROWS;                            // 32 KB

    preprocess_kernel<<<N_ROWS, 256, 0, stream>>>(img, txt, scale_p, imgbf, txtbf,
                                                  diag, row_sum, col_sum);

    dim3 grid(N_ROWS / 256, N_ROWS / 256);
    gemm_exp_kernel<<<grid, 512, 0, stream>>>(imgbf, txtbf, row_sum, col_sum);

    finish_kernel<<<1, 256, 0, stream>>>(row_sum, col_sum, diag, out);
}

// Round 6
// 269.291 us; speedup vs baseline: 1.2424x; 1.0613x over previous
//
#include <hip/hip_runtime.h>
#include <stdint.h>

#define N_ROWS 8192
#define D_DIM  1024
#define BK     64

typedef __attribute__((ext_vector_type(8))) __bf16 bf16x8;
typedef __attribute__((ext_vector_type(8))) short  short8;
typedef __attribute__((ext_vector_type(4))) float  f32x4;

#define GLD16(gptr, lptr) __builtin_amdgcn_global_load_lds( \
    (const __attribute__((address_space(1))) void*)(gptr),  \
    (__attribute__((address_space(3))) void*)(lptr), 16, 0, 0)

__device__ __forceinline__ unsigned short f2bf(float v) {
    unsigned int u = __float_as_uint(v);
    u += 0x7fffu + ((u >> 16) & 1u);   // RNE
    return (unsigned short)(u >> 16);
}

// Fused: img -> bf16 (pre-scaled by logit_scale*log2e), txt -> bf16,
// exact fp32 diag[i] = scale * dot(img[i], txt[i]), and zero-init of
// the row/col sum accumulators (replaces a separate memset dispatch).
// One block per row; 256 threads, one float4 of each input per thread.
__global__ void preprocess_kernel(const float* __restrict__ img,
                                  const float* __restrict__ txt,
                                  const float* __restrict__ scale_p,
                                  short* __restrict__ imgbf,
                                  short* __restrict__ txtbf,
                                  float* __restrict__ diag,
                                  float* __restrict__ row_sum,
                                  float* __restrict__ col_sum) {
    const int row = blockIdx.x;
    const int tid = threadIdx.x;
    const float sc = *scale_p;
    const float f  = sc * 1.44269504088896340736f;   // fold log2(e) for exp2 epilogue

    const float4 x = ((const float4*)(img + (size_t)row * D_DIM))[tid];
    const float4 y = ((const float4*)(txt + (size_t)row * D_DIM))[tid];

    short4 oi, ot;
    oi.x = (short)f2bf(x.x * f); oi.y = (short)f2bf(x.y * f);
    oi.z = (short)f2bf(x.z * f); oi.w = (short)f2bf(x.w * f);
    ot.x = (short)f2bf(y.x);     ot.y = (short)f2bf(y.y);
    ot.z = (short)f2bf(y.z);     ot.w = (short)f2bf(y.w);
    ((short4*)(imgbf + (size_t)row * D_DIM))[tid] = oi;
    ((short4*)(txtbf + (size_t)row * D_DIM))[tid] = ot;

    float s = x.x * y.x + x.y * y.y + x.z * y.z + x.w * y.w;
#pragma unroll
    for (int m = 1; m < 64; m <<= 1) s += __shfl_xor(s, m);
    __shared__ float ws[4];
    if ((tid & 63) == 0) ws[tid >> 6] = s;
    __syncthreads();
    if (tid == 0) {
        diag[row]    = (ws[0] + ws[1] + ws[2] + ws[3]) * sc;
        row_sum[row] = 0.f;
        col_sum[row] = 0.f;
    }
}

// Round-0 GEMM (best measured: 162 us, MfmaUtil 38%, 0 bank conflicts,
// ~3 blocks/CU implicit overlap). 128x128 tile, 4 waves, BK=64,
// global_load_lds staging with XOR-swizzled source, epilogue
// e = exp2(acc) + in-wave row/col reductions + atomics.
__global__ void gemm_exp_kernel(const short* __restrict__ A,   // img bf16, scaled
                                const short* __restrict__ B,   // txt bf16
                                float* __restrict__ row_sum,
                                float* __restrict__ col_sum) {
    __shared__ __align__(16) short As[128 * BK];
    __shared__ __align__(16) short Bs[128 * BK];

    const int tid  = threadIdx.x;
    const int lane = tid & 63;
    const int w    = tid >> 6;      // wave 0..3
    const int wr   = w >> 1;        // wave row (0..1)
    const int wc   = w & 1;         // wave col (0..1)
    const int ti   = blockIdx.y * 128;
    const int tj   = blockIdx.x * 128;

    const int quad = lane >> 4;
    const int l15  = lane & 15;

    // staging: lane -> (row-within-chunk, swizzled k-chunk)
    const int srow = lane >> 3;               // 0..7
    const int sg   = (lane & 7) ^ srow;       // global 16B k-chunk after XOR swizzle

    f32x4 acc[4][4];
#pragma unroll
    for (int i = 0; i < 4; i++)
#pragma unroll
        for (int j = 0; j < 4; j++) acc[i][j] = (f32x4){0.f, 0.f, 0.f, 0.f};

    const int arow = wr * 64 + l15;   // + fr*16  -> LDS row for a-frag
    const int brow = wc * 64 + l15;   // + fc*16  -> LDS row for b-frag

    for (int k0 = 0; k0 < D_DIM; k0 += BK) {
        // ---- stage A,B tiles (each wave: 4 chunks of 1KB per tile) ----
#pragma unroll
        for (int c = 0; c < 4; c++) {
            const int ch = w * 4 + c;             // 0..15, wave-uniform
            const int r  = ch * 8 + srow;         // tile row 0..127
            const short* ga = A + (size_t)(ti + r) * D_DIM + k0 + sg * 8;
            const short* gb = B + (size_t)(tj + r) * D_DIM + k0 + sg * 8;
            GLD16(ga, As + ch * 512);
            GLD16(gb, Bs + ch * 512);
        }
        __syncthreads();
        // ---- compute ----
#pragma unroll
        for (int kk = 0; kk < 2; kk++) {
            bf16x8 af[4], bfb[4];
#pragma unroll
            for (int fr = 0; fr < 4; fr++) {
                const int row = arow + fr * 16;
                const int kc  = ((kk << 2) + quad) ^ (row & 7);
                af[fr] = *(const bf16x8*)(As + row * BK + kc * 8);
            }
#pragma unroll
            for (int fc = 0; fc < 4; fc++) {
                const int row = brow + fc * 16;
                const int kc  = ((kk << 2) + quad) ^ (row & 7);
                bfb[fc] = *(const bf16x8*)(Bs + row * BK + kc * 8);
            }
#pragma unroll
            for (int fr = 0; fr < 4; fr++)
#pragma unroll
                for (int fc = 0; fc < 4; fc++)
                    acc[fr][fc] = __builtin_amdgcn_mfma_f32_16x16x32_bf16(
                        af[fr], bfb[fc], acc[fr][fc], 0, 0, 0);
        }
        __syncthreads();
    }

    // ---- epilogue: e = 2^acc, then row/col reductions ----
#pragma unroll
    for (int fr = 0; fr < 4; fr++)
#pragma unroll
        for (int fc = 0; fc < 4; fc++)
#pragma unroll
            for (int r = 0; r < 4; r++)
                acc[fr][fc][r] = __builtin_amdgcn_exp2f(acc[fr][fc][r]);

    // row sums: element (fr,fc,r) is logits[ti + wr*64 + fr*16 + quad*4 + r][tj + wc*64 + fc*16 + l15]
    const int rowbase = ti + wr * 64;
#pragma unroll
    for (int fr = 0; fr < 4; fr++) {
#pragma unroll
        for (int r = 0; r < 4; r++) {
            float s = acc[fr][0][r] + acc[fr][1][r] + acc[fr][2][r] + acc[fr][3][r];
            s += __shfl_xor(s, 1);
            s += __shfl_xor(s, 2);
            s += __shfl_xor(s, 4);
            s += __shfl_xor(s, 8);
            if (l15 == 0)
                atomicAdd(&row_sum[rowbase + fr * 16 + quad * 4 + r], s);
        }
    }

    // col sums
    const int colbase = tj + wc * 64;
#pragma unroll
    for (int fc = 0; fc < 4; fc++) {
        float s = 0.f;
#pragma unroll
        for (int fr = 0; fr < 4; fr++)
#pragma unroll
            for (int r = 0; r < 4; r++) s += acc[fr][fc][r];
        s += __shfl_xor(s, 16);
        s += __shfl_xor(s, 32);
        if (quad == 0)
            atomicAdd(&col_sum[colbase + fc * 16 + l15], s);
    }
}

__global__ void finish_kernel(const float* __restrict__ rs, const float* __restrict__ cs,
                              const float* __restrict__ diag, float* __restrict__ out) {
    const int tid  = threadIdx.x;
    const int lane = tid & 63;
    const int w    = tid >> 6;
    float s = 0.f;
    for (int i = tid; i < N_ROWS; i += 256)
        s += logf(rs[i]) + logf(cs[i]) - 2.0f * diag[i];
#pragma unroll
    for (int m = 1; m < 64; m <<= 1) s += __shfl_xor(s, m);
    __shared__ float wsum[4];
    if (lane == 0) wsum[w] = s;
    __syncthreads();
    if (tid == 0)
        out[0] = (wsum[0] + wsum[1] + wsum[2] + wsum[3]) * (0.5f / (float)N_ROWS);
}

extern "C" void kernel_launch(void* const* d_in, const int* in_sizes, int n_in,
                              void* d_out, int out_size, void* d_ws, size_t ws_size,
                              hipStream_t stream) {
    const float* img     = (const float*)d_in[0];
    const float* txt     = (const float*)d_in[1];
    const float* scale_p = (const float*)d_in[2];
    float* out = (float*)d_out;

    char* ws = (char*)d_ws;
    short* imgbf   = (short*)ws;                                  // 16 MB
    short* txtbf   = (short*)(ws + (size_t)16 * 1024 * 1024);     // 16 MB
    float* row_sum = (float*)(ws + (size_t)32 * 1024 * 1024);     // 32 KB
    float* col_sum = row_sum + N_ROWS;                            // 32 KB
    float* diag    = col_sum + N_ROWS;                            // 32 KB

    preprocess_kernel<<<N_ROWS, 256, 0, stream>>>(img, txt, scale_p, imgbf, txtbf,
                                                  diag, row_sum, col_sum);

    dim3 grid(N_ROWS / 128, N_ROWS / 128);
    gemm_exp_kernel<<<grid, 256, 0, stream>>>(imgbf, txtbf, row_sum, col_sum);

    finish_kernel<<<1, 256, 0, stream>>>(row_sum, col_sum, diag, out);
}